// Round 6
// baseline (151.015 us; speedup 1.0000x reference)
//
#include <hip/hip_runtime.h>

#define BB 8192
#define TT 512
#define II 5
#define HH 16
#define TC 32                       // steps per LDS chunk
#define NC (TT / TC)                // 16 chunks
#define CHUNK_BYTES (16 * TC * 32)  // 16 batches * 32 steps * 32B records

typedef _Float16 half_t;
typedef _Float16 half4 __attribute__((ext_vector_type(4)));
typedef __fp16 fp16x2 __attribute__((ext_vector_type(2)));
typedef float floatx4 __attribute__((ext_vector_type(4)));

__device__ __forceinline__ float fast_sigmoid(float x) {
    float e = __builtin_amdgcn_exp2f(x * -1.4426950408889634f);
    return __builtin_amdgcn_rcpf(1.0f + e);
}
__device__ __forceinline__ float fast_tanh(float x) {
    float e = __builtin_amdgcn_exp2f(x * 2.8853900817779268f);
    return fmaf(-2.0f, __builtin_amdgcn_rcpf(e + 1.0f), 1.0f);
}

__device__ __forceinline__ void gl_lds16(const void* g, void* l) {
    __builtin_amdgcn_global_load_lds(
        (const __attribute__((address_space(1))) void*)g,
        (__attribute__((address_space(3))) void*)l, 16, 0, 0);
}

// Per-wave GRU: 16 batches / wave. MFMA 16x16x16 f16, D-layout == B-layout so
// the gate output feeds the next step's B operand in-lane (no cross-lane).
// x staged via global_load_lds DMA into double-buffered LDS, counted vmcnt.
// LDS record (jb, s): 32 B at jb*1024 + s*32. half0 = x[0:3], half1 = x[1:4].
__global__ __launch_bounds__(64)
void gru_fwd_kernel(const float* __restrict__ x,
                    const float* __restrict__ W_ih,
                    const float* __restrict__ W_hh,
                    const float* __restrict__ b_ih,
                    const float* __restrict__ b_hh,
                    const float* __restrict__ W_fc,
                    const float* __restrict__ b_fc,
                    float* __restrict__ out) {
    __shared__ __align__(16) char ldsbuf[2][CHUNK_BYTES];

    const int lane = threadIdx.x;   // 0..63
    const int jb   = lane & 15;     // batch within tile (B/D column, A row)
    const int q    = lane >> 4;     // k-group
    const int b0   = blockIdx.x * 16;

    // ---- resident A-fragments: W_hh gate rows; W_ih rows zero-padded to K=16
    half4 wa_r, wa_z, wa_n, wx_r, wx_z, wx_n;
#pragma unroll
    for (int j = 0; j < 4; ++j) {
        int k = 4 * q + j;
        wa_r[j] = (half_t)W_hh[(0 * HH + jb) * HH + k];
        wa_z[j] = (half_t)W_hh[(1 * HH + jb) * HH + k];
        wa_n[j] = (half_t)W_hh[(2 * HH + jb) * HH + k];
        float vr = (k < II) ? W_ih[(0 * HH + jb) * II + k] : 0.0f;
        float vz = (k < II) ? W_ih[(1 * HH + jb) * II + k] : 0.0f;
        float vn = (k < II) ? W_ih[(2 * HH + jb) * II + k] : 0.0f;
        wx_r[j] = (half_t)vr; wx_z[j] = (half_t)vz; wx_n[j] = (half_t)vn;
    }

    // ---- bias C-fragments (row = 4q+i, uniform over batch columns)
    floatx4 cb_r, cb_z, cb_xn, cb_hn;
#pragma unroll
    for (int i = 0; i < 4; ++i) {
        int r = 4 * q + i;
        cb_r[i]  = b_ih[r] + b_hh[r];
        cb_z[i]  = b_ih[HH + r] + b_hh[HH + r];
        cb_xn[i] = b_ih[2 * HH + r];
        cb_hn[i] = b_hh[2 * HH + r];
    }

    // ---- loop-carried state
    half4 bh = {};                                        // h as B-fragment
    float hf0 = 0.0f, hf1 = 0.0f, hf2 = 0.0f, hf3 = 0.0f; // h rows 4q+i (f32)

    // ---- DMA source addressing
    // granule for instr k, lane l: batch = k, step = l>>1, half = l&1
    // src byte = x + ((b0+k)*TT + t0 + (l>>1))*20 + (l&1)*4
    const char* xb = (const char*)x + (size_t)b0 * TT * II * 4
                   + (size_t)(lane >> 1) * II * 4 + (size_t)(lane & 1) * 4;

#define ISSUE(C)                                                              \
    do {                                                                      \
        if ((C) < NC) {                                                       \
            const char* sb_ = xb + (size_t)(C) * TC * II * 4;                 \
            char* db_ = &ldsbuf[(C) & 1][0];                                  \
            _Pragma("unroll")                                                 \
            for (int k_ = 0; k_ < 16; ++k_)                                   \
                gl_lds16(sb_ + (size_t)k_ * TT * II * 4, db_ + k_ * 1024);    \
        }                                                                     \
    } while (0)

    // One GRU step; PF = raw 16B record half (q0: x0..x3, q1: x1..x4).
#define STEP(PF)                                                              \
    do {                                                                      \
        half4 bx = {};                                                        \
        if (q == 0) {                                                         \
            fp16x2 l0_ = __builtin_amdgcn_cvt_pkrtz(PF[0], PF[1]);            \
            fp16x2 l1_ = __builtin_amdgcn_cvt_pkrtz(PF[2], PF[3]);            \
            bx[0] = (half_t)l0_[0]; bx[1] = (half_t)l0_[1];                   \
            bx[2] = (half_t)l1_[0]; bx[3] = (half_t)l1_[1];                   \
        } else if (q == 1) {                                                  \
            bx[0] = (half_t)PF[3];                                            \
        }                                                                     \
        floatx4 cx_r = __builtin_amdgcn_mfma_f32_16x16x16f16(wx_r, bx, cb_r, 0, 0, 0); \
        floatx4 cx_z = __builtin_amdgcn_mfma_f32_16x16x16f16(wx_z, bx, cb_z, 0, 0, 0); \
        floatx4 cx_n = __builtin_amdgcn_mfma_f32_16x16x16f16(wx_n, bx, cb_xn, 0, 0, 0); \
        floatx4 d_r  = __builtin_amdgcn_mfma_f32_16x16x16f16(wa_r, bh, cx_r, 0, 0, 0); \
        floatx4 d_z  = __builtin_amdgcn_mfma_f32_16x16x16f16(wa_z, bh, cx_z, 0, 0, 0); \
        floatx4 d_n  = __builtin_amdgcn_mfma_f32_16x16x16f16(wa_n, bh, cb_hn, 0, 0, 0); \
        float r0 = fast_sigmoid(d_r[0]), z0 = fast_sigmoid(d_z[0]);           \
        float n0 = fast_tanh(fmaf(r0, d_n[0], cx_n[0]));                      \
        hf0 = fmaf(z0, hf0 - n0, n0);                                         \
        float r1 = fast_sigmoid(d_r[1]), z1 = fast_sigmoid(d_z[1]);           \
        float n1 = fast_tanh(fmaf(r1, d_n[1], cx_n[1]));                      \
        hf1 = fmaf(z1, hf1 - n1, n1);                                         \
        float r2 = fast_sigmoid(d_r[2]), z2 = fast_sigmoid(d_z[2]);           \
        float n2 = fast_tanh(fmaf(r2, d_n[2], cx_n[2]));                      \
        hf2 = fmaf(z2, hf2 - n2, n2);                                         \
        float r3 = fast_sigmoid(d_r[3]), z3 = fast_sigmoid(d_z[3]);           \
        float n3 = fast_tanh(fmaf(r3, d_n[3], cx_n[3]));                      \
        hf3 = fmaf(z3, hf3 - n3, n3);                                         \
        fp16x2 lo_ = __builtin_amdgcn_cvt_pkrtz(hf0, hf1);                    \
        fp16x2 hi_ = __builtin_amdgcn_cvt_pkrtz(hf2, hf3);                    \
        bh[0] = (half_t)lo_[0]; bh[1] = (half_t)lo_[1];                       \
        bh[2] = (half_t)hi_[0]; bh[3] = (half_t)hi_[1];                       \
    } while (0)

    ISSUE(0);
    ISSUE(1);

    for (int c = 0; c < NC; ++c) {
        // Wait for chunk c's 16 loads; keep chunk c+1's 16 in flight.
        if (c == NC - 1) asm volatile("s_waitcnt vmcnt(0)" ::: "memory");
        else             asm volatile("s_waitcnt vmcnt(16)" ::: "memory");

        const char* myrec = &ldsbuf[c & 1][0] + jb * 1024 + (q == 1 ? 16 : 0);

        floatx4 pfA = {}, pfB = {};
        if (lane < 32) pfA = *(const floatx4*)(myrec);
#pragma unroll
        for (int s = 0; s < TC; s += 2) {
            if (lane < 32) pfB = *(const floatx4*)(myrec + (s + 1) * 32);
            STEP(pfA);
            if (lane < 32 && s + 2 < TC) pfA = *(const floatx4*)(myrec + (s + 2) * 32);
            STEP(pfB);
        }

        ISSUE(c + 2);   // after all reads of buf[c&1]; lands well before use
    }
#undef ISSUE
#undef STEP

    // ---- out[b] = dot(W_fc, h) + b_fc ; reduce across the 4 k-groups
    float p = hf0 * W_fc[4 * q + 0];
    p = fmaf(hf1, W_fc[4 * q + 1], p);
    p = fmaf(hf2, W_fc[4 * q + 2], p);
    p = fmaf(hf3, W_fc[4 * q + 3], p);
    p += __shfl_xor(p, 16);
    p += __shfl_xor(p, 32);
    if (q == 0) out[b0 + jb] = p + b_fc[0];
}

extern "C" void kernel_launch(void* const* d_in, const int* in_sizes, int n_in,
                              void* d_out, int out_size, void* d_ws, size_t ws_size,
                              hipStream_t stream) {
    const float* x    = (const float*)d_in[0];
    const float* W_ih = (const float*)d_in[1];
    const float* W_hh = (const float*)d_in[2];
    const float* b_ih = (const float*)d_in[3];
    const float* b_hh = (const float*)d_in[4];
    const float* W_fc = (const float*)d_in[5];
    const float* b_fc = (const float*)d_in[6];
    float* out = (float*)d_out;

    dim3 grid(BB / 16);   // one 64-lane wave per 16 batches
    dim3 block(64);
    gru_fwd_kernel<<<grid, block, 0, stream>>>(x, W_ih, W_hh, b_ih, b_hh, W_fc, b_fc, out);
}